// Round 1
// baseline (625.777 us; speedup 1.0000x reference)
//
#include <hip/hip_runtime.h>

// upfirdn2d, up=2, down=1, pad=(2,1), taps [1,3,3,1], gain 4.
// Input  x : (16,128,128,128) f32  -> 2048 channel-images of 128x128
// Output y : (16,128,256,256) f32  -> 2048 channel-images of 256x256
//
// Polyphase (separable taps [0.25,0.75,0.75,0.25] per axis):
//   even out 2m  : 0.25*x[m-1] + 0.75*x[m]
//   odd  out 2m+1: 0.75*x[m]   + 0.25*x[m+1]
//
// One 64-lane wave per output row; lane t produces out cols 4t..4t+3 from
// vertically-filtered input cols 2t-1..2t+2 (neighbors via wave shuffles).

#define IN_H   128
#define IN_W   128
#define OUT_W  256
#define ROWS_PER_CH 256  // output rows per channel image

__global__ __launch_bounds__(256) void upfirdn2d_up2_kernel(
    const float* __restrict__ x, float* __restrict__ out, int nrows_total)
{
    const int lane = threadIdx.x & 63;
    const int waves_per_block = blockDim.x >> 6;           // 4
    int rid = blockIdx.x * waves_per_block + (threadIdx.x >> 6);
    const int rstride = gridDim.x * waves_per_block;

    for (; rid < nrows_total; rid += rstride) {
        const int ch = rid >> 8;          // rid / 256
        const int oy = rid & 255;
        const int m  = oy >> 1;
        const int p  = oy & 1;            // vertical phase

        // contributing input rows + weights
        int   rA = p ? m     : m - 1;
        int   rB = p ? m + 1 : m;
        float wA = p ? 0.75f : 0.25f;
        float wB = p ? 0.25f : 0.75f;
        if (rA < 0)        { rA = 0;        wA = 0.0f; }   // top edge (oy==0)
        if (rB >= IN_H)    { rB = IN_H - 1; wB = 0.0f; }   // bottom edge (oy==255)

        const float* base = x + (size_t)ch * (IN_H * IN_W);
        const float2 a = *(const float2*)(base + rA * IN_W + 2 * lane);
        const float2 b = *(const float2*)(base + rB * IN_W + 2 * lane);

        // vertically filtered input cols 2t and 2t+1
        const float v0 = wA * a.x + wB * b.x;
        const float v1 = wA * a.y + wB * b.y;

        // neighbors: filtered col 2t-1 (from lane-1) and 2t+2 (from lane+1)
        float left  = __shfl_up(v1, 1);
        float right = __shfl_down(v0, 1);
        if (lane == 0)  left  = 0.0f;     // x[-1] = 0 (zero pad)
        if (lane == 63) right = 0.0f;     // x[128] = 0 (zero pad)

        float4 o;
        o.x = 0.25f * left + 0.75f * v0;   // out col 4t   (even, m=2t)
        o.y = 0.75f * v0   + 0.25f * v1;   // out col 4t+1 (odd,  m=2t)
        o.z = 0.25f * v0   + 0.75f * v1;   // out col 4t+2 (even, m=2t+1)
        o.w = 0.75f * v1   + 0.25f * right;// out col 4t+3 (odd,  m=2t+1)

        *(float4*)(out + (size_t)rid * OUT_W + 4 * lane) = o;
    }
}

extern "C" void kernel_launch(void* const* d_in, const int* in_sizes, int n_in,
                              void* d_out, int out_size, void* d_ws, size_t ws_size,
                              hipStream_t stream) {
    const float* x = (const float*)d_in[0];
    // d_in[1] (fir_kernel) is a fixed [1,3,3,1] outer-product * 4/64 — taps
    // are baked in as the exact fp32 constants 0.25/0.75.
    float* out = (float*)d_out;

    const int nrows = out_size / OUT_W;   // 2048 * 256 = 524288 output rows
    const int block = 256;                // 4 waves -> 4 rows per block-pass
    const int grid  = 8192;               // grid-stride, 16 row-passes/block

    upfirdn2d_up2_kernel<<<grid, block, 0, stream>>>(x, out, nrows);
}

// Round 3
// 619.207 us; speedup vs baseline: 1.0106x; 1.0106x over previous
//
#include <hip/hip_runtime.h>

// upfirdn2d, up=2, down=1, pad=(2,1), taps [1,3,3,1], gain 4.
// Input  x : (16,128,128,128) f32  -> 2048 channel-images of 128x128
// Output y : (16,128,256,256) f32  -> 2048 channel-images of 256x256
//
// Separable polyphase (taps [0.25,0.75,0.75,0.25] per axis):
//   horizontal: lane t loads float2 {x[2t], x[2t+1]} of a row and produces
//     out cols 4t..4t+3 via wave shuffles (zero pad at col edges).
//   vertical:   out row 2m   = 0.25*h[m-1] + 0.75*h[m]
//               out row 2m+1 = 0.75*h[m]   + 0.25*h[m+1]
//
// One wave streams a 32-input-row strip of one channel: each input row is
// loaded ONCE, h-filtered ONCE, and blended with the previous filtered row
// to emit two output rows. Read amplification 34/32; no LDS.
// 2048 channels x 4 strips = 8192 waves = 32 waves/CU (full occupancy).

#define IN_H   128
#define IN_W   128
#define OUT_W  256
#define STRIP  32          // input rows per wave

__device__ __forceinline__ float4 hfilt(float2 a, int lane) {
    float left  = __shfl_up(a.y, 1);     // filtered col 2t-1 source
    float right = __shfl_down(a.x, 1);   // filtered col 2t+2 source
    if (lane == 0)  left  = 0.0f;        // zero pad x[-1]
    if (lane == 63) right = 0.0f;        // zero pad x[128]
    float4 h;
    h.x = 0.25f * left + 0.75f * a.x;    // out col 4t
    h.y = 0.75f * a.x  + 0.25f * a.y;    // out col 4t+1
    h.z = 0.25f * a.x  + 0.75f * a.y;    // out col 4t+2
    h.w = 0.75f * a.y  + 0.25f * right;  // out col 4t+3
    return h;
}

__global__ __launch_bounds__(256) void upfirdn2d_up2_strip_kernel(
    const float* __restrict__ x, float* __restrict__ out)
{
    const int lane = threadIdx.x & 63;
    const int wid  = blockIdx.x * (blockDim.x >> 6) + (threadIdx.x >> 6);
    const int ch   = wid >> 2;           // channel image 0..2047
    const int s    = wid & 3;            // strip 0..3
    const int m0   = s << 5;             // first input row of strip

    const float* base  = x   + (size_t)ch * (IN_H * IN_W) + 2 * lane;
    float*       obase = out + (size_t)ch * (OUT_W * OUT_W) + 4 * lane;

    // previous filtered row h[m0-1] (zeros for the top strip: x[-1] = 0 pad)
    float4 prev;
    if (m0 == 0) {
        prev = make_float4(0.f, 0.f, 0.f, 0.f);
    } else {
        prev = hfilt(*(const float2*)(base + (size_t)(m0 - 1) * IN_W), lane);
    }

    // i = 0: emit only out row 2*m0 (row 2*m0-1 belongs to the strip above)
    {
        float4 h = hfilt(*(const float2*)(base + (size_t)m0 * IN_W), lane);
        float4 o;
        o.x = 0.25f * prev.x + 0.75f * h.x;
        o.y = 0.25f * prev.y + 0.75f * h.y;
        o.z = 0.25f * prev.z + 0.75f * h.z;
        o.w = 0.25f * prev.w + 0.75f * h.w;
        *(float4*)(obase + (size_t)(2 * m0) * OUT_W) = o;
        prev = h;
    }

    #pragma unroll 4
    for (int i = 1; i <= STRIP; ++i) {
        const int m = m0 + i;
        float2 a = (m < IN_H) ? *(const float2*)(base + (size_t)m * IN_W)
                              : make_float2(0.f, 0.f);   // x[128] = 0 pad
        float4 h = hfilt(a, lane);

        float* p = obase + (size_t)(2 * m - 1) * OUT_W;
        float4 o1;                                // odd row 2m-1
        o1.x = 0.75f * prev.x + 0.25f * h.x;
        o1.y = 0.75f * prev.y + 0.25f * h.y;
        o1.z = 0.75f * prev.z + 0.25f * h.z;
        o1.w = 0.75f * prev.w + 0.25f * h.w;
        *(float4*)p = o1;

        if (i < STRIP) {                          // even row 2m
            float4 o2;
            o2.x = 0.25f * prev.x + 0.75f * h.x;
            o2.y = 0.25f * prev.y + 0.75f * h.y;
            o2.z = 0.25f * prev.z + 0.75f * h.z;
            o2.w = 0.25f * prev.w + 0.75f * h.w;
            *(float4*)(p + OUT_W) = o2;
        }
        prev = h;
    }
}

extern "C" void kernel_launch(void* const* d_in, const int* in_sizes, int n_in,
                              void* d_out, int out_size, void* d_ws, size_t ws_size,
                              hipStream_t stream) {
    const float* x = (const float*)d_in[0];
    // d_in[1] (fir_kernel) is the fixed [1,3,3,1] outer product * 4/64;
    // separable taps 0.25/0.75 are baked in as exact fp32 constants.
    float* out = (float*)d_out;

    // 2048 channel-images x 4 strips = 8192 waves; 4 waves per 256-thr block.
    const int block = 256;
    const int grid  = 2048;
    upfirdn2d_up2_strip_kernel<<<grid, block, 0, stream>>>(x, out);
}